// Round 1
// 119.655 us; speedup vs baseline: 1.0095x; 1.0095x over previous
//
#include <hip/hip_runtime.h>
#include <hip/hip_bf16.h>

#if defined(__has_builtin)
#if __has_builtin(__builtin_amdgcn_exp2f)
#define EXP2F __builtin_amdgcn_exp2f
#endif
#if __has_builtin(__builtin_amdgcn_rcpf)
#define RCPF __builtin_amdgcn_rcpf
#endif
#endif
#ifndef EXP2F
#define EXP2F exp2f
#endif
#ifndef RCPF
#define RCPF(x) (1.0f / (x))
#endif

// Sizes (fixed by the problem)
#define B_  8
#define Q_  256
#define K_  1024
#define D_  256
#define H_  128
#define DV_ 128

#define CSL 2.8853900817779268f   // 2*log2(e)
#define L2E 1.4426950408889634f   // log2(e)

// Workspace layout (floats). Total ~5.25 MB (known-safe).
#define QE_OFF   0                // qE   [B*Q][H]               = 262144 floats
#define KE_OFF   262144           // kET4 [B][32 g][K] float4    = 1048576 floats
#define WPK_OFF  1310720          // wpk  [32][8] floats         = 256

// ---------------------------------------------------------------------------
// proj_kernel: 160 blocks, 64 rows x 128 cols per block, NOW 512 threads
// (2 waves/SIMD for latency hiding; was 1). Thread tile 2 rows x 8 cols,
// with the 8 cols split into {c4, 64+c4} so each Ws ds_read_b128 covers 16
// consecutive 16B chunks per wave -> 2-way bank aliasing (free) instead of
// the old 4-way conflict at 32B stride.
// Epilogue: exp2(CSL*x); q rows -> qE row-major; k rows -> kET4[b][g][k]
// float4 (E_{4g}..E_{4g+3}) so attn loads ONE dwordx4 per 4-h group.
// ---------------------------------------------------------------------------
__global__ __launch_bounds__(512) void proj_kernel(
    const float* __restrict__ queries, const float* __restrict__ keys,
    const float* __restrict__ Wq, const float* __restrict__ Wk,
    const float* __restrict__ w_v,
    float* __restrict__ qE, float4* __restrict__ kET4, float* __restrict__ wpk)
{
    __shared__ __align__(16) float As[64][68];   // [d][row], pad 68 (272B rows, 16B aligned)
    __shared__ __align__(16) float Ws[64][128];  // [d][col]

    const int tid = threadIdx.x;
    const int blk = blockIdx.x;
    const bool isQ = blk < 32;                   // 32*64 = 2048 q rows
    const int row0 = isQ ? blk * 64 : (blk - 32) * 64;
    const float* A = isQ ? (queries + row0 * D_) : (keys + row0 * D_);
    const float* W = isQ ? Wq : Wk;

    float acc[2][8];
#pragma unroll
    for (int i = 0; i < 2; i++)
#pragma unroll
        for (int j = 0; j < 8; j++) acc[i][j] = 0.f;

    const int lr  = tid & 63;          // A-stage row (consecutive lanes -> conflict-free LDS write)
    const int ldb = (tid >> 6) * 8;    // A-stage d base (8 floats = 2 float4 per thread)
    const int r2  = (tid >> 4) * 2;    // compute row base 0..62
    const int c4  = (tid & 15) * 4;    // compute col base 0..60 (cols c4 and 64+c4)

    for (int d0 = 0; d0 < D_; d0 += 64) {
        // stage A transposed: As[d][row]; each lane streams 32B consecutive
        // (other 32B of the 64B line is taken by lane+64 -> L1 hit)
#pragma unroll
        for (int j = 0; j < 2; j++) {
            const float4 a = *(const float4*)&A[lr * D_ + d0 + ldb + j * 4];
            As[ldb + j * 4 + 0][lr] = a.x;
            As[ldb + j * 4 + 1][lr] = a.y;
            As[ldb + j * 4 + 2][lr] = a.z;
            As[ldb + j * 4 + 3][lr] = a.w;
        }
        // stage W: 64 x 128, coalesced float4
#pragma unroll
        for (int l = 0; l < 4; l++) {
            const int idx = tid + l * 512;
            const int rr = idx >> 5, cc = (idx & 31) * 4;
            *(float4*)&Ws[rr][cc] = *(const float4*)&W[(d0 + rr) * H_ + cc];
        }
        __syncthreads();
#pragma unroll 4
        for (int d = 0; d < 64; d++) {
            const float2 a2 = *(const float2*)&As[d][r2];      // broadcast across 16 lanes
            const float4 w0 = *(const float4*)&Ws[d][c4];      // 16 consecutive chunks/wave
            const float4 w1 = *(const float4*)&Ws[d][c4 + 64]; // 2-way aliasing only
            acc[0][0] = fmaf(a2.x, w0.x, acc[0][0]);
            acc[0][1] = fmaf(a2.x, w0.y, acc[0][1]);
            acc[0][2] = fmaf(a2.x, w0.z, acc[0][2]);
            acc[0][3] = fmaf(a2.x, w0.w, acc[0][3]);
            acc[0][4] = fmaf(a2.x, w1.x, acc[0][4]);
            acc[0][5] = fmaf(a2.x, w1.y, acc[0][5]);
            acc[0][6] = fmaf(a2.x, w1.z, acc[0][6]);
            acc[0][7] = fmaf(a2.x, w1.w, acc[0][7]);
            acc[1][0] = fmaf(a2.y, w0.x, acc[1][0]);
            acc[1][1] = fmaf(a2.y, w0.y, acc[1][1]);
            acc[1][2] = fmaf(a2.y, w0.z, acc[1][2]);
            acc[1][3] = fmaf(a2.y, w0.w, acc[1][3]);
            acc[1][4] = fmaf(a2.y, w1.x, acc[1][4]);
            acc[1][5] = fmaf(a2.y, w1.y, acc[1][5]);
            acc[1][6] = fmaf(a2.y, w1.z, acc[1][6]);
            acc[1][7] = fmaf(a2.y, w1.w, acc[1][7]);
        }
        __syncthreads();
    }

#pragma unroll
    for (int i = 0; i < 2; i++) {
        float e[8];
#pragma unroll
        for (int j = 0; j < 8; j++) e[j] = EXP2F(CSL * acc[i][j]);
        const int row = row0 + r2 + i;
        if (isQ) {
            float* dst = qE + row * H_;
            *(float4*)(dst + c4)      = make_float4(e[0], e[1], e[2], e[3]);
            *(float4*)(dst + 64 + c4) = make_float4(e[4], e[5], e[6], e[7]);
        } else {
            const int b = row >> 10, k = row & 1023;   // 64-row tiles never cross b
            const int g1 = c4 >> 2;                    // group of cols c4..c4+3
            kET4[(size_t)(b * 32 + g1) * K_ + k]      = make_float4(e[0], e[1], e[2], e[3]);
            kET4[(size_t)(b * 32 + 16 + g1) * K_ + k] = make_float4(e[4], e[5], e[6], e[7]);
        }
    }

    // wpk[g*8..]: (w1,w2,w1+w2,0, w3,w4,w3+w4,0) with w' = -2*log2(e)*w_v
    if (blk == 0 && tid < 32) {
        const float4 wv = *(const float4*)&w_v[tid * 4];
        const float w1 = -2.0f * L2E * wv.x;
        const float w2 = -2.0f * L2E * wv.y;
        const float w3 = -2.0f * L2E * wv.z;
        const float w4 = -2.0f * L2E * wv.w;
        *(float4*)&wpk[tid * 8]     = make_float4(w1, w2, w1 + w2, 0.f);
        *(float4*)&wpk[tid * 8 + 4] = make_float4(w3, w4, w3 + w4, 0.f);
    }
}

// ---------------------------------------------------------------------------
// attn_kernel: 1024 threads, 1 k per thread, 4 q-rows per block.
// NEW: (a) 4-way h-pairing: Sum_{i=1..4} wi/(1+xi) = [n12*d34+n34*d12]/(d12*d34)
//      -> one v_rcp per 4 h's per q-row (was 2), one dwordx4 k-load per group
//      (was 2x dwordx2). Products bounded by e^{2*sum4(q+k)} ~ e^35 max: safe.
// (b) XCD-pair swizzle: 1-D grid 512; XCD = id%8 serves batches {x,(x+4)%8}
//      -> 2MB L2 working set per XCD (kET4[b]+values[b] for 2 b's), with
//      2-batch load-balance averaging preserved.
// Masked-k skip unchanged; AV k-loop clamped to vl. Exact: masked p = 0.
// ---------------------------------------------------------------------------
__global__ __launch_bounds__(1024, 8) void attn_kernel(
    const float* __restrict__ qE,       // [B*Q][H] = e^{2q}
    const float4* __restrict__ kET4,    // [B][32][K] = (e^{2k}) 4-groups
    const float* __restrict__ values,   // [B][K][DV]
    const int*   __restrict__ valid_lens,
    const float* __restrict__ wpk,      // [32][8] floats
    float* __restrict__ out)            // [B][Q][DV]
{
    __shared__ __align__(16) float sc[K_][4];        // 16 KB p-values
    __shared__ __align__(16) float red[16][4][128];  // 32 KB AV reduction
    __shared__ __align__(16) float psum[16][4];
    __shared__ float rl[4];

    const int tid = threadIdx.x;
    // XCD-pair swizzle (dispatch round-robins linear id over 8 XCDs):
    const int id = blockIdx.x;          // 0..511
    const int x8 = id & 7;
    const int j8 = id >> 3;             // 0..63
    const int b  = (j8 & 1) ? ((x8 + 4) & 7) : x8;
    const int qt = (j8 >> 1) | ((j8 & 1) << 5);   // 0..63, bijective per b
    const int q0 = qt * 4;
    const int vl = valid_lens[b];

    const float* q0p = qE + (b * Q_ + q0) * H_;
    const float* q1p = q0p + H_;
    const float* q2p = q0p + 2 * H_;
    const float* q3p = q0p + 3 * H_;
    const float4* kb4 = kET4 + (size_t)(b * 32) * K_ + tid;

    float acc0 = 0.f, acc1 = 0.f, acc2 = 0.f, acc3 = 0.f;

    if (tid < vl) {
#pragma unroll 2
        for (int g = 0; g < 32; g++) {
            const float4 ek = kb4[(size_t)g * K_];
            const float4 wa = *(const float4*)&wpk[g * 8];      // (w1,w2,w12,-)
            const float4 wb = *(const float4*)&wpk[g * 8 + 4];  // (w3,w4,w34,-)
            const float4 qa = *(const float4*)&q0p[4 * g];
            const float4 qb = *(const float4*)&q1p[4 * g];
            const float4 qc = *(const float4*)&q2p[4 * g];
            const float4 qd = *(const float4*)&q3p[4 * g];
#define ROW4(QV, ACC)                                                     \
            {                                                             \
                const float x1 = QV.x * ek.x, x2 = QV.y * ek.y;           \
                const float x3 = QV.z * ek.z, x4 = QV.w * ek.w;           \
                const float e1 = x1 + 1.f;                                \
                const float d12 = fmaf(e1, x2, e1);                       \
                const float e3 = x3 + 1.f;                                \
                const float d34 = fmaf(e3, x4, e3);                       \
                float n12 = fmaf(wa.y, x1, wa.z);                         \
                n12 = fmaf(wa.x, x2, n12);                                \
                float n34 = fmaf(wb.y, x3, wb.z);                         \
                n34 = fmaf(wb.x, x4, n34);                                \
                float Nn = n12 * d34;                                     \
                Nn = fmaf(n34, d12, Nn);                                  \
                const float Dd = d12 * d34;                               \
                ACC = fmaf(Nn, RCPF(Dd), ACC);                            \
            }
            ROW4(qa, acc0)
            ROW4(qb, acc1)
            ROW4(qc, acc2)
            ROW4(qd, acc3)
#undef ROW4
        }
    }

    // ---- exp + mask + row sums (k = tid) ----
    const bool valid = tid < vl;
    float4 pv;
    pv.x = valid ? EXP2F(acc0) : 0.f;
    pv.y = valid ? EXP2F(acc1) : 0.f;
    pv.z = valid ? EXP2F(acc2) : 0.f;
    pv.w = valid ? EXP2F(acc3) : 0.f;
    *(float4*)&sc[tid][0] = pv;

    float4 s = pv;
#pragma unroll
    for (int sh = 32; sh > 0; sh >>= 1) {
        s.x += __shfl_xor(s.x, sh);
        s.y += __shfl_xor(s.y, sh);
        s.z += __shfl_xor(s.z, sh);
        s.w += __shfl_xor(s.w, sh);
    }
    const int lane = tid & 63, w = tid >> 6;
    if (lane == 0) *(float4*)&psum[w][0] = s;
    __syncthreads();
    if (tid < 4) {
        float t = 0.f;
#pragma unroll
        for (int ww = 0; ww < 16; ww++) t += psum[ww][tid];
        rl[tid] = RCPF(t);
    }

    // ---- AV: thread = (kc 0..15, kh 0..1, vg 0..31), k-loop clamped to vl ----
    const int vg = (tid & 31) * 4;
    const int kh = (tid >> 5) & 1;
    const int kc = tid >> 6;
    const float* vb = values + (size_t)b * (K_ * DV_) + vg;
    float av[4][4];
#pragma unroll
    for (int q = 0; q < 4; q++)
#pragma unroll
        for (int jj = 0; jj < 4; jj++) av[q][jj] = 0.f;

    const int rem = vl - kc * 64 - kh;
    const int imax = rem <= 0 ? 0 : (((rem + 1) >> 1) > 32 ? 32 : ((rem + 1) >> 1));
#pragma unroll 2
    for (int i = 0; i < imax; i++) {
        const int k = kc * 64 + i * 2 + kh;
        const float4 vv = *(const float4*)&vb[k * DV_];
        const float4 p = *(const float4*)&sc[k][0];
        av[0][0] = fmaf(p.x, vv.x, av[0][0]); av[0][1] = fmaf(p.x, vv.y, av[0][1]);
        av[0][2] = fmaf(p.x, vv.z, av[0][2]); av[0][3] = fmaf(p.x, vv.w, av[0][3]);
        av[1][0] = fmaf(p.y, vv.x, av[1][0]); av[1][1] = fmaf(p.y, vv.y, av[1][1]);
        av[1][2] = fmaf(p.y, vv.z, av[1][2]); av[1][3] = fmaf(p.y, vv.w, av[1][3]);
        av[2][0] = fmaf(p.z, vv.x, av[2][0]); av[2][1] = fmaf(p.z, vv.y, av[2][1]);
        av[2][2] = fmaf(p.z, vv.z, av[2][2]); av[2][3] = fmaf(p.z, vv.w, av[2][3]);
        av[3][0] = fmaf(p.w, vv.x, av[3][0]); av[3][1] = fmaf(p.w, vv.y, av[3][1]);
        av[3][2] = fmaf(p.w, vv.z, av[3][2]); av[3][3] = fmaf(p.w, vv.w, av[3][3]);
    }
    // fold kh pairs (threads tid and tid^32 hold same (kc,vg))
#pragma unroll
    for (int q = 0; q < 4; q++)
#pragma unroll
        for (int jj = 0; jj < 4; jj++) av[q][jj] += __shfl_xor(av[q][jj], 32);
    if (kh == 0) {
#pragma unroll
        for (int q = 0; q < 4; q++)
            *(float4*)&red[kc][q][vg] = make_float4(av[q][0], av[q][1], av[q][2], av[q][3]);
    }
    __syncthreads();

    if (tid < 512) {
        const int q = tid >> 7, v = tid & 127;
        float t = 0.f;
#pragma unroll
        for (int g = 0; g < 16; g++) t += red[g][q][v];
        out[(b * Q_ + q0 + q) * DV_ + v] = t * rl[q];
    }
}

extern "C" void kernel_launch(void* const* d_in, const int* in_sizes, int n_in,
                              void* d_out, int out_size, void* d_ws, size_t ws_size,
                              hipStream_t stream) {
    const float* queries    = (const float*)d_in[0];  // [8,256,256]
    const float* keys       = (const float*)d_in[1];  // [8,1024,256]
    const float* values     = (const float*)d_in[2];  // [8,1024,128]
    const int*   valid_lens = (const int*)d_in[3];    // [8]
    const float* W_q        = (const float*)d_in[4];  // [256,128]
    const float* W_k        = (const float*)d_in[5];  // [256,128]
    const float* w_v        = (const float*)d_in[6];  // [128]
    float* out = (float*)d_out;

    float*  ws   = (float*)d_ws;
    float*  qE   = ws + QE_OFF;
    float4* kET4 = (float4*)(ws + KE_OFF);
    float*  wpk  = ws + WPK_OFF;

    proj_kernel<<<160, 512, 0, stream>>>(queries, keys, W_q, W_k, w_v, qE, kET4, wpk);
    attn_kernel<<<512, 1024, 0, stream>>>(qE, kET4, values, valid_lens, wpk, out);
}